// Round 6
// baseline (291.735 us; speedup 1.0000x reference)
//
#include <hip/hip_runtime.h>
#include <hip/hip_bf16.h>
#include <hip/hip_cooperative_groups.h>

namespace cg = cooperative_groups;

// TripletLoss N=8192, D=128. Round 6: cooperative single-kernel (512 blocks,
// 2 blocks/CU needed vs >=4 capacity) with occupancy-gated fallback to the
// proven round-4 four-kernel path.
// Math (both paths): MFMA C init = -(x2i+x2j)/2 so acc = -d2/2;
// s = sqrt(max(-acc,5e-9)), dist = sqrt2*s; neg weight exp(-dist); pos weight
// exp(dist-30) (shift-stabilized, includes self at e^-30 ~ 9e-14, excluded by
// the pl>1e-12 validity test in finalize).

typedef __bf16 bf16x8 __attribute__((ext_vector_type(8)));
typedef float f32x4 __attribute__((ext_vector_type(4)));

#define NROWS 8192
#define DIM 128
#define JSPLIT 8
#define JSPAN (NROWS / JSPLIT)     // 1024
#define NBLK 512                   // 64 i-blocks x 8 j-slices
#define MARGIN_F 0.3f
#define SQRT2_F 1.41421356f

// ======================= cooperative fused kernel =======================
__global__ __launch_bounds__(256, 4) void fused_kernel(
        const float* __restrict__ F,
        const int* __restrict__ labels,
        __hip_bfloat16* __restrict__ Fb,
        float* __restrict__ x2,
        float4* __restrict__ partial,
        float2* __restrict__ bpart,
        float* __restrict__ out) {
    __shared__ bf16x8 sB[1024];          // 16 KB; chunk c = (jt*4+kc)*64 + lane
    __shared__ int sLab[64];
    __shared__ float sX2h[64];           // -0.5 * x2j
    __shared__ float rS[4], rC[4];

    cg::grid_group grid = cg::this_grid();

    const int tid = threadIdx.x;
    const int bid = blockIdx.x;
    const int wave = tid >> 6, lane = tid & 63;
    const int quad = lane >> 4, lm = lane & 15;

    // -------- phase 0: fp32->bf16 cast + row norms (16 rows/block) --------
    {
        const int row = bid * 16 + (tid >> 4);
        const int c8 = tid & 15;                     // 16 threads/row, 32B each
        const float4* src = (const float4*)(F + (size_t)row * DIM);
        float4 f0 = src[c8 * 2], f1 = src[c8 * 2 + 1];
        __hip_bfloat16* dst = Fb + (size_t)row * DIM + c8 * 8;
        ((__hip_bfloat162*)dst)[0] = __float22bfloat162_rn(make_float2(f0.x, f0.y));
        ((__hip_bfloat162*)dst)[1] = __float22bfloat162_rn(make_float2(f0.z, f0.w));
        ((__hip_bfloat162*)dst)[2] = __float22bfloat162_rn(make_float2(f1.x, f1.y));
        ((__hip_bfloat162*)dst)[3] = __float22bfloat162_rn(make_float2(f1.z, f1.w));
        float ss = f0.x * f0.x + f0.y * f0.y + f0.z * f0.z + f0.w * f0.w
                 + f1.x * f1.x + f1.y * f1.y + f1.z * f1.z + f1.w * f1.w;
#pragma unroll
        for (int m = 8; m > 0; m >>= 1) ss += __shfl_xor(ss, m, 64);
        if (c8 == 0) x2[row] = ss;
    }
    grid.sync();

    // -------- phase 1: fused GEMM + mining --------
    {
        const int iblk = bid & 63;
        const int jslice = bid >> 6;                 // 0..7
        const int wbase = iblk * 128 + wave * 32;    // this wave's 32 i-rows
        const int j0 = jslice * JSPAN;

        // A fragments: 2 row-groups x 4 K-chunks; A[m=lm][k=quad*8+j]
        bf16x8 a[2][4];
#pragma unroll
        for (int g = 0; g < 2; ++g)
#pragma unroll
            for (int kc = 0; kc < 4; ++kc)
                a[g][kc] = *(const bf16x8*)(Fb + (size_t)(wbase + g * 16 + lm) * DIM
                                            + kc * 32 + quad * 8);

        // C/D: col(n)=lm (j), row(m)=quad*4+r (i); idx = g*4+r
        float x2ih[8]; int labi[8];
#pragma unroll
        for (int g = 0; g < 2; ++g)
#pragma unroll
            for (int r = 0; r < 4; ++r) {
                int row = wbase + g * 16 + quad * 4 + r;
                x2ih[g * 4 + r] = -0.5f * x2[row];
                labi[g * 4 + r] = labels[row];
            }

        float nl[8], ns[8], pl[8], ps[8];
#pragma unroll
        for (int i = 0; i < 8; ++i) { nl[i] = 0.f; ns[i] = 0.f; pl[i] = 0.f; ps[i] = 0.f; }

        // staging: chunk c = tid + s*256; jt=c>>8, kc=(c>>6)&3, lane=c&63
        int srcoff[4];
#pragma unroll
        for (int s = 0; s < 4; ++s) {
            int c = tid + s * 256;
            int kc = (c >> 6) & 3, jt = c >> 8;
            srcoff[s] = (jt * 16 + lm) * DIM + kc * 32 + quad * 8;
        }

        for (int jb = 0; jb < JSPAN / 64; ++jb) {    // 16 tiles
            const int jbase = j0 + jb * 64;
            __syncthreads();
#pragma unroll
            for (int s = 0; s < 4; ++s)
                sB[tid + s * 256] = *(const bf16x8*)(Fb + (size_t)jbase * DIM + srcoff[s]);
            if (tid < 64) {
                sLab[tid] = labels[jbase + tid];
                sX2h[tid] = -0.5f * x2[jbase + tid];
            }
            __syncthreads();

#pragma unroll
            for (int jt = 0; jt < 4; ++jt) {
                const float xjh = sX2h[jt * 16 + lm];
                const int labj = sLab[jt * 16 + lm];
                f32x4 acc0, acc1;
#pragma unroll
                for (int r = 0; r < 4; ++r) {
                    acc0[r] = x2ih[r] + xjh;
                    acc1[r] = x2ih[4 + r] + xjh;
                }
#pragma unroll
                for (int kc = 0; kc < 4; ++kc) {
                    bf16x8 b = sB[(jt * 4 + kc) * 64 + lane];    // lane-linear
                    acc0 = __builtin_amdgcn_mfma_f32_16x16x32_bf16(a[0][kc], b, acc0, 0, 0, 0);
                    acc1 = __builtin_amdgcn_mfma_f32_16x16x32_bf16(a[1][kc], b, acc1, 0, 0, 0);
                }
#pragma unroll
                for (int g = 0; g < 2; ++g)
#pragma unroll
                    for (int r = 0; r < 4; ++r) {
                        const int idx = g * 4 + r;
                        float av = (g == 0) ? acc0[r] : acc1[r];
                        float d2h = fmaxf(-av, 5e-9f);
                        float s = __builtin_amdgcn_sqrtf(d2h);
                        float ne = __expf(-SQRT2_F * s);
                        bool same = (labj == labi[idx]);
                        float mne = same ? 0.f : ne;
                        nl[idx] += mne;
                        ns[idx] = fmaf(mne, s, ns[idx]);
                        if (same) {                              // rare (~0.2%)
                            float pe = __expf(fmaf(SQRT2_F, s, -30.f));
                            pl[idx] += pe;
                            ps[idx] = fmaf(pe, s, ps[idx]);
                        }
                    }
            }
        }

#pragma unroll
        for (int m = 1; m < 16; m <<= 1)
#pragma unroll
            for (int i = 0; i < 8; ++i) {
                nl[i] += __shfl_xor(nl[i], m, 64);
                ns[i] += __shfl_xor(ns[i], m, 64);
                pl[i] += __shfl_xor(pl[i], m, 64);
                ps[i] += __shfl_xor(ps[i], m, 64);
            }
        if (lm == 0) {
#pragma unroll
            for (int g = 0; g < 2; ++g)
#pragma unroll
                for (int r = 0; r < 4; ++r) {
                    int row = wbase + g * 16 + quad * 4 + r;
                    partial[(size_t)jslice * NROWS + row] =
                        make_float4(pl[g * 4 + r], ps[g * 4 + r], nl[g * 4 + r], ns[g * 4 + r]);
                }
        }
    }
    grid.sync();

    // -------- phase 2: per-row loss -> block partial (16 rows/block) --------
    {
        float sum = 0.f, cnt = 0.f;
        if (tid < 16) {
            const int row = bid * 16 + tid;
            float pls = 0.f, pss = 0.f, nls = 0.f, nss = 0.f;
            for (int s2 = 0; s2 < JSPLIT; ++s2) {
                float4 p = partial[(size_t)s2 * NROWS + row];
                pls += p.x; pss += p.y; nls += p.z; nss += p.w;
            }
            if (pls > 1e-12f && nls > 0.f) {
                float x = fmaf(SQRT2_F, pss / pls - nss / nls, MARGIN_F);
                sum = fmaxf(x, 0.f) + log1pf(__expf(-fabsf(x)));
                cnt = 1.f;
            }
#pragma unroll
            for (int m = 1; m < 16; m <<= 1) {
                sum += __shfl_xor(sum, m, 64);
                cnt += __shfl_xor(cnt, m, 64);
            }
            if (tid == 0) bpart[bid] = make_float2(sum, cnt);
        }
    }
    grid.sync();

    // -------- phase 3: scalar --------
    if (bid == 0) {
        float s = 0.f, c = 0.f;
        for (int k = tid; k < NBLK; k += 256) {
            float2 b = bpart[k];
            s += b.x; c += b.y;
        }
#pragma unroll
        for (int m = 32; m > 0; m >>= 1) {
            s += __shfl_xor(s, m, 64);
            c += __shfl_xor(c, m, 64);
        }
        if (lane == 0) { rS[wave] = s; rC[wave] = c; }
        __syncthreads();
        if (tid == 0)
            out[0] = (rS[0] + rS[1] + rS[2] + rS[3]) /
                     fmaxf(rC[0] + rC[1] + rC[2] + rC[3], 1.0f);
    }
}

// ======================= fallback path (round-4, proven) =======================
#define JTILE 64
#define LDS_STRIDE 136

__global__ __launch_bounds__(256) void prep_kernel(const float* __restrict__ F,
                                                   __hip_bfloat16* __restrict__ Fb,
                                                   float* __restrict__ x2,
                                                   float* __restrict__ gstat) {
    const int tid = threadIdx.x;
    const int wave = tid >> 6, lane = tid & 63;
    const int row = blockIdx.x * 4 + wave;
    float2 f = ((const float2*)(F + (size_t)row * DIM))[lane];
    ((__hip_bfloat162*)(Fb + (size_t)row * DIM))[lane] = __float22bfloat162_rn(f);
    float ss = f.x * f.x + f.y * f.y;
#pragma unroll
    for (int m = 32; m > 0; m >>= 1) ss += __shfl_xor(ss, m, 64);
    if (lane == 0) x2[row] = ss;
    if (blockIdx.x == 0 && tid < 2) gstat[tid] = 0.f;
}

__global__ __launch_bounds__(256, 6) void pairs_kernel(
        const __hip_bfloat16* __restrict__ Fb,
        const float* __restrict__ x2,
        const int* __restrict__ labels,
        float4* __restrict__ partial) {
    __shared__ __hip_bfloat16 sB[JTILE * LDS_STRIDE];
    __shared__ int sLab[JTILE];
    __shared__ float sX2h[JTILE];
    const int tid = threadIdx.x;
    const int wave = tid >> 6, lane = tid & 63;
    const int quad = lane >> 4, lm = lane & 15;
    const int rbase = blockIdx.x * 64 + wave * 16;
    bf16x8 a[4];
#pragma unroll
    for (int kc = 0; kc < 4; ++kc)
        a[kc] = *(const bf16x8*)(Fb + (size_t)(rbase + lm) * DIM + kc * 32 + quad * 8);
    int ig[4]; float x2ih[4]; int labi[4];
#pragma unroll
    for (int r = 0; r < 4; ++r) {
        ig[r] = rbase + quad * 4 + r;
        x2ih[r] = -0.5f * x2[ig[r]];
        labi[r] = labels[ig[r]];
    }
    float nl4[4] = {0,0,0,0}, ns4[4] = {0,0,0,0};
    float pl4[4] = {0,0,0,0}, ps4[4] = {0,0,0,0};
    const int j0 = blockIdx.y * JSPAN;
    for (int jb = 0; jb < JSPAN / JTILE; ++jb) {
        const int jbase = j0 + jb * JTILE;
        __syncthreads();
#pragma unroll
        for (int s = 0; s < 4; ++s) {
            int c = tid + s * 256;
            int jr = c >> 4, ck = c & 15;
            *(bf16x8*)(sB + jr * LDS_STRIDE + ck * 8) =
                *(const bf16x8*)(Fb + (size_t)(jbase + jr) * DIM + ck * 8);
        }
        if (tid < JTILE) {
            sLab[tid] = labels[jbase + tid];
            sX2h[tid] = -0.5f * x2[jbase + tid];
        }
        __syncthreads();
#pragma unroll
        for (int jt = 0; jt < 4; ++jt) {
            const int jl = jt * 16 + lm;
            const __hip_bfloat16* bp = sB + jl * LDS_STRIDE + quad * 8;
            const float xjh = sX2h[jl];
            f32x4 acc;
#pragma unroll
            for (int r = 0; r < 4; ++r) acc[r] = x2ih[r] + xjh;
#pragma unroll
            for (int kc = 0; kc < 4; ++kc) {
                bf16x8 b = *(const bf16x8*)(bp + kc * 32);
                acc = __builtin_amdgcn_mfma_f32_16x16x32_bf16(a[kc], b, acc, 0, 0, 0);
            }
            const int labj = sLab[jl];
#pragma unroll
            for (int r = 0; r < 4; ++r) {
                float d2h = fmaxf(-acc[r], 5e-9f);
                float s = __builtin_amdgcn_sqrtf(d2h);
                float ne = __expf(-SQRT2_F * s);
                bool same = (labj == labi[r]);
                float mne = same ? 0.f : ne;
                nl4[r] += mne;
                ns4[r] = fmaf(mne, s, ns4[r]);
                if (same) {
                    float pe = __expf(fmaf(SQRT2_F, s, -30.f));
                    pl4[r] += pe;
                    ps4[r] = fmaf(pe, s, ps4[r]);
                }
            }
        }
    }
#pragma unroll
    for (int m = 1; m < 16; m <<= 1)
#pragma unroll
        for (int r = 0; r < 4; ++r) {
            pl4[r] += __shfl_xor(pl4[r], m, 64);
            ps4[r] += __shfl_xor(ps4[r], m, 64);
            nl4[r] += __shfl_xor(nl4[r], m, 64);
            ns4[r] += __shfl_xor(ns4[r], m, 64);
        }
    if (lm == 0)
#pragma unroll
        for (int r = 0; r < 4; ++r)
            partial[(size_t)blockIdx.y * NROWS + ig[r]] =
                make_float4(pl4[r], ps4[r], nl4[r], ns4[r]);
}

__global__ __launch_bounds__(256) void finalize_kernel(const float4* __restrict__ partial,
                                                       float* __restrict__ gstat) {
    const int row = blockIdx.x * 256 + threadIdx.x;
    float pl = 0.f, ps = 0.f, nl = 0.f, ns = 0.f;
    for (int s = 0; s < JSPLIT; ++s) {
        float4 p = partial[(size_t)s * NROWS + row];
        pl += p.x; ps += p.y; nl += p.z; ns += p.w;
    }
    float sum = 0.f, cnt = 0.f;
    if (pl > 1e-12f && nl > 0.f) {
        float x = fmaf(SQRT2_F, ps / pl - ns / nl, MARGIN_F);
        sum = fmaxf(x, 0.f) + log1pf(__expf(-fabsf(x)));
        cnt = 1.f;
    }
#pragma unroll
    for (int m = 32; m > 0; m >>= 1) {
        sum += __shfl_xor(sum, m, 64);
        cnt += __shfl_xor(cnt, m, 64);
    }
    __shared__ float sS[4], sC[4];
    const int wave = threadIdx.x >> 6, lane = threadIdx.x & 63;
    if (lane == 0) { sS[wave] = sum; sC[wave] = cnt; }
    __syncthreads();
    if (threadIdx.x == 0) {
        unsafeAtomicAdd(&gstat[0], sS[0] + sS[1] + sS[2] + sS[3]);
        unsafeAtomicAdd(&gstat[1], sC[0] + sC[1] + sC[2] + sC[3]);
    }
}

__global__ void div_kernel(const float* __restrict__ gstat, float* __restrict__ out) {
    out[0] = gstat[0] / fmaxf(gstat[1], 1.0f);
}

// ======================= launcher =======================
extern "C" void kernel_launch(void* const* d_in, const int* in_sizes, int n_in,
                              void* d_out, int out_size, void* d_ws, size_t ws_size,
                              hipStream_t stream) {
    const float* F = (const float*)d_in[0];
    const int* labels = (const int*)d_in[1];
    float* out = (float*)d_out;

    char* ws = (char*)d_ws;
    __hip_bfloat16* Fb = (__hip_bfloat16*)ws;                      // 2 MB
    size_t off = (size_t)NROWS * DIM * 2;
    float* x2 = (float*)(ws + off); off += (size_t)NROWS * 4;      // 32 KB
    float2* bpart = (float2*)(ws + off); off += NBLK * 8;          // 4 KB
    float* gstat = (float*)(ws + off); off += 64;                  // fallback scratch
    float4* partial = (float4*)(ws + off);                         // 1 MB (JSPLIT=8)

    // occupancy-gated cooperative path: need 2 blocks/CU for 512 blocks
    int blocksPerCU = 0;
    hipError_t qerr = hipOccupancyMaxActiveBlocksPerMultiprocessor(
        &blocksPerCU, (const void*)fused_kernel, 256, 0);
    bool coop = (qerr == hipSuccess) && (blocksPerCU >= 2);

    if (coop) {
        void* args[] = {(void*)&F, (void*)&labels, (void*)&Fb, (void*)&x2,
                        (void*)&partial, (void*)&bpart, (void*)&out};
        hipError_t lerr = hipLaunchCooperativeKernel(
            (const void*)fused_kernel, dim3(NBLK), dim3(256), args, 0, stream);
        if (lerr == hipSuccess) return;
    }

    // fallback: proven four-kernel path
    prep_kernel<<<NROWS / 4, 256, 0, stream>>>(F, Fb, x2, gstat);
    pairs_kernel<<<dim3(NROWS / 64, JSPLIT), 256, 0, stream>>>(Fb, x2, labels, partial);
    finalize_kernel<<<NROWS / 256, 256, 0, stream>>>(partial, gstat);
    div_kernel<<<1, 1, 0, stream>>>(gstat, out);
}